// Round 3
// baseline (871.859 us; speedup 1.0000x reference)
//
#include <hip/hip_runtime.h>

#define B 8
#define N 4096
#define NITER 4
#define CHUNK 64                 // P rows per block
#define NCHUNK (N / CHUNK)       // 64 row chunks
#define COLT 4                   // column tiles of 1024 cols
#define TPB 1024
#define NBLK (COLT * NCHUNK)     // 256 blocks = 1 per CU -> co-resident
#define BN (B * N)

// Manual grid barrier: generation-based, agent-scope atomics.
// __threadfence() = agent-scope fence -> handles cross-XCD L2 writeback/invalidate.
__device__ __forceinline__ void grid_barrier(unsigned* cnt, unsigned* gen) {
    __threadfence();
    __syncthreads();
    if (threadIdx.x == 0) {
        unsigned g = __hip_atomic_load(gen, __ATOMIC_RELAXED, __HIP_MEMORY_SCOPE_AGENT);
        unsigned a = __hip_atomic_fetch_add(cnt, 1u, __ATOMIC_ACQ_REL, __HIP_MEMORY_SCOPE_AGENT);
        if (a == NBLK - 1u) {
            __hip_atomic_store(cnt, 0u, __ATOMIC_RELAXED, __HIP_MEMORY_SCOPE_AGENT);
            __hip_atomic_fetch_add(gen, 1u, __ATOMIC_RELEASE, __HIP_MEMORY_SCOPE_AGENT);
        } else {
            while (__hip_atomic_load(gen, __ATOMIC_ACQUIRE, __HIP_MEMORY_SCOPE_AGENT) == g) {
                __builtin_amdgcn_s_sleep(8);
            }
        }
    }
    __syncthreads();
    __threadfence();
}

__global__ __launch_bounds__(TPB, 4)
void diffusion_persistent(const float* __restrict__ preds_in,
                          const float* __restrict__ P,
                          const int* __restrict__ seed_idx,
                          int nseeds,
                          float* __restrict__ out,
                          float* __restrict__ ws) {
    unsigned* cnt = (unsigned*)ws;
    unsigned* gen = cnt + 1;
    float* partial = ws + 64;    // 2 buffers x [NCHUNK][B][N] = 2 x 8 MiB

    __shared__ __align__(16) float predLds[B * CHUNK];   // [i][r], 2 KiB

    const int tx      = threadIdx.x;
    const int chunk   = blockIdx.x >> 2;     // 0..63  (row chunk)
    const int coltile = blockIdx.x & 3;      // 0..3
    const int base_r  = chunk * CHUNK;
    const int a       = coltile * TPB + tx;  // this thread's output column

    // ---- prologue: this column's 64 P rows -> registers (P read from HBM once) ----
    float Pq[CHUNK];
#pragma unroll
    for (int r = 0; r < CHUNK; ++r)
        Pq[r] = P[(size_t)(base_r + r) * N + a];   // coalesced: lanes = consecutive a

    // seed membership for the stage element this thread owns (valid for tx < 512)
    const int si = tx >> 6;              // batch
    const int sr = tx & 63;              // row within chunk
    const int se = si * N + base_r + sr; // flat [i][row] element index
    bool is_seed = false;
    for (int k = 0; k < nseeds; ++k)
        is_seed |= (seed_idx[2 * k] * N + seed_idx[2 * k + 1]) == se;

    // stage iteration-0 pred slice
    if (tx < B * CHUNK)
        predLds[tx] = preds_in[se];
    __syncthreads();

    int buf = 0;
    for (int it = 0; it < NITER; ++it) {
        // ---- compute: partial product over this block's 64 rows, all 8 batches ----
        float prod[B];
#pragma unroll
        for (int i = 0; i < B; ++i) prod[i] = 1.0f;

        const float4* pl4 = (const float4*)predLds;
#pragma unroll
        for (int rq = 0; rq < CHUNK / 4; ++rq) {
#pragma unroll
            for (int i = 0; i < B; ++i) {
                float4 pv = pl4[i * (CHUNK / 4) + rq];   // broadcast ds_read_b128
                float t0 = fmaf(-Pq[4 * rq + 0], pv.x, 1.0f);
                float t1 = fmaf(-Pq[4 * rq + 1], pv.y, 1.0f);
                float t2 = fmaf(-Pq[4 * rq + 2], pv.z, 1.0f);
                float t3 = fmaf(-Pq[4 * rq + 3], pv.w, 1.0f);
                prod[i] *= (t0 * t1) * (t2 * t3);
            }
        }

        float* pb = partial + (size_t)buf * (NCHUNK * BN);
#pragma unroll
        for (int i = 0; i < B; ++i)
            pb[(size_t)(chunk * B + i) * N + a] = prod[i];   // coalesced

        grid_barrier(cnt, gen);   // double-buffered partials -> one barrier/iter

        // ---- stage: combine all 64 chunk-partials for the pred slice we need next ----
        if (tx < B * CHUNK) {
            const float* col = pb + se;
            float p0 = 1.f, p1 = 1.f, p2 = 1.f, p3 = 1.f;
#pragma unroll
            for (int c = 0; c < NCHUNK; c += 4) {
                p0 *= col[(size_t)(c + 0) * BN];
                p1 *= col[(size_t)(c + 1) * BN];
                p2 *= col[(size_t)(c + 2) * BN];
                p3 *= col[(size_t)(c + 3) * BN];
            }
            float v = 1.0f - ((p0 * p1) * (p2 * p3));
            if (is_seed) v = 1.0f;
            predLds[tx] = v;
            if (it == NITER - 1 && coltile == 0)
                out[se] = v;     // 64 chunk-blocks x 512 = full [B][N]
        }
        __syncthreads();
        buf ^= 1;
    }
}

extern "C" void kernel_launch(void* const* d_in, const int* in_sizes, int n_in,
                              void* d_out, int out_size, void* d_ws, size_t ws_size,
                              hipStream_t stream) {
    const float* preds    = (const float*)d_in[0];   // [B, N]
    const float* P        = (const float*)d_in[1];   // [N, N]
    const int*   seed_idx = (const int*)d_in[2];     // [NSEEDS, 2]
    int nseeds = in_sizes[2] / 2;

    float* out = (float*)d_out;
    float* ws  = (float*)d_ws;

    // zero the barrier counters (ws is re-poisoned to 0xAA before every launch)
    hipMemsetAsync(ws, 0, 256, stream);
    diffusion_persistent<<<NBLK, TPB, 0, stream>>>(preds, P, seed_idx, nseeds, out, ws);
}

// Round 4
// 840.203 us; speedup vs baseline: 1.0377x; 1.0377x over previous
//
#include <hip/hip_runtime.h>

#define B 8
#define N 4096
#define NITER 4
#define CHUNK 64                  // P rows per block
#define NCHUNK (N / CHUNK)        // 64 row chunks
#define TPB 1024
#define COLT (N / TPB)            // 4 column tiles
#define NBLK (COLT * NCHUNK)      // 256 blocks = 1 per CU (co-resident)
#define BN (B * N)

// Pin a value into a VGPR: opaque asm def -> compiler cannot remat/reload it.
#define PIN(x) asm("" : "+v"(x))

#define FOR16(M) M(0) M(1) M(2) M(3) M(4) M(5) M(6) M(7) \
                 M(8) M(9) M(10) M(11) M(12) M(13) M(14) M(15)

// 64 P values as explicit scalars (no array -> no alloca -> no scratch).
#define PDECL(k) float P##k##0, P##k##1, P##k##2, P##k##3;

#define PLOAD(k) \
    P##k##0 = Pp[(size_t)(4 * k + 0) * N]; \
    P##k##1 = Pp[(size_t)(4 * k + 1) * N]; \
    P##k##2 = Pp[(size_t)(4 * k + 2) * N]; \
    P##k##3 = Pp[(size_t)(4 * k + 3) * N]; \
    PIN(P##k##0); PIN(P##k##1); PIN(P##k##2); PIN(P##k##3);

// One 4-row group for one batch: 4 fma + 3 mul + 1 mul.
#define ONE(k, b, acc) { \
    const float4 pv = pl4[(b) * (CHUNK / 4) + (k)]; \
    const float t0 = fmaf(-P##k##0, pv.x, 1.0f); \
    const float t1 = fmaf(-P##k##1, pv.y, 1.0f); \
    const float t2 = fmaf(-P##k##2, pv.z, 1.0f); \
    const float t3 = fmaf(-P##k##3, pv.w, 1.0f); \
    acc *= (t0 * t1) * (t2 * t3); }

#define GROUP(k) ONE(k, 0, a0) ONE(k, 1, a1) ONE(k, 2, a2) ONE(k, 3, a3) \
                 ONE(k, 4, a4) ONE(k, 5, a5) ONE(k, 6, a6) ONE(k, 7, a7)

// Grid barrier: release via acq_rel fetch_add; waiters spin RELAXED (no
// per-iteration cache invalidate), then ONE acquire load for ordering.
__device__ __forceinline__ void grid_barrier(unsigned* cnt, unsigned* gen) {
    __threadfence();
    __syncthreads();
    if (threadIdx.x == 0) {
        unsigned g = __hip_atomic_load(gen, __ATOMIC_RELAXED, __HIP_MEMORY_SCOPE_AGENT);
        unsigned a = __hip_atomic_fetch_add(cnt, 1u, __ATOMIC_ACQ_REL, __HIP_MEMORY_SCOPE_AGENT);
        if (a == NBLK - 1u) {
            __hip_atomic_store(cnt, 0u, __ATOMIC_RELAXED, __HIP_MEMORY_SCOPE_AGENT);
            __hip_atomic_fetch_add(gen, 1u, __ATOMIC_RELEASE, __HIP_MEMORY_SCOPE_AGENT);
        } else {
            while (__hip_atomic_load(gen, __ATOMIC_RELAXED, __HIP_MEMORY_SCOPE_AGENT) == g)
                __builtin_amdgcn_s_sleep(2);
            (void)__hip_atomic_load(gen, __ATOMIC_ACQUIRE, __HIP_MEMORY_SCOPE_AGENT);
        }
    }
    __syncthreads();
    __threadfence();
}

__global__ __launch_bounds__(TPB, 4)
void diffusion_persistent(const float* __restrict__ preds_in,
                          const float* __restrict__ Pg,
                          const int* __restrict__ seed_idx,
                          int nseeds,
                          float* __restrict__ out,
                          float* __restrict__ ws) {
    unsigned* cnt = (unsigned*)ws;
    unsigned* gen = cnt + 1;
    float* partial = ws + 64;     // 2 buffers x [NCHUNK][B][N] = 2 x 8 MiB

    __shared__ __align__(16) float predLds[B * CHUNK];   // [batch][row], 2 KiB

    const int tx      = threadIdx.x;
    const int chunk   = blockIdx.x >> 2;     // 0..63  row chunk
    const int coltile = blockIdx.x & 3;      // 0..3
    const int base_r  = chunk * CHUNK;
    const int a       = coltile * TPB + tx;  // this thread's output column

    const float* Pp = Pg + (size_t)base_r * N + a;

    // seed membership + iter-0 pred slice for the stage element this thread owns
    const int se = (tx >> 6) * N + base_r + (tx & 63);   // [batch][row] flat
    bool is_seed = false;
    for (int k = 0; k < nseeds; ++k)
        is_seed |= (seed_idx[2 * k] * N + seed_idx[2 * k + 1]) == se;
    if (tx < B * CHUNK)
        predLds[tx] = preds_in[se];
    __syncthreads();

    const float4* pl4 = (const float4*)predLds;

    FOR16(PDECL)
    FOR16(PLOAD)                // 64 coalesced loads: P from HBM exactly once

    int buf = 0;
    for (int it = 0; it < NITER; ++it) {
        float a0 = 1.f, a1 = 1.f, a2 = 1.f, a3 = 1.f,
              a4 = 1.f, a5 = 1.f, a6 = 1.f, a7 = 1.f;

        FOR16(GROUP)            // 64 rows x 8 batches, all operands reg/LDS

        float* pb = partial + (size_t)buf * ((size_t)NCHUNK * BN);
        pb[(size_t)(chunk * B + 0) * N + a] = a0;
        pb[(size_t)(chunk * B + 1) * N + a] = a1;
        pb[(size_t)(chunk * B + 2) * N + a] = a2;
        pb[(size_t)(chunk * B + 3) * N + a] = a3;
        pb[(size_t)(chunk * B + 4) * N + a] = a4;
        pb[(size_t)(chunk * B + 5) * N + a] = a5;
        pb[(size_t)(chunk * B + 6) * N + a] = a6;
        pb[(size_t)(chunk * B + 7) * N + a] = a7;

        grid_barrier(cnt, gen);     // double-buffered partials -> 1 barrier/iter

        // stage: combine 64 chunk-partials for the pred slice we need next iter
        if (tx < B * CHUNK) {
            const float* col = pb + se;
            float q0 = 1.f, q1 = 1.f, q2 = 1.f, q3 = 1.f;
#pragma unroll 4
            for (int c = 0; c < NCHUNK; c += 4) {
                q0 *= col[(size_t)(c + 0) * BN];
                q1 *= col[(size_t)(c + 1) * BN];
                q2 *= col[(size_t)(c + 2) * BN];
                q3 *= col[(size_t)(c + 3) * BN];
            }
            float v = 1.0f - ((q0 * q1) * (q2 * q3));
            if (is_seed) v = 1.0f;
            predLds[tx] = v;
            if (it == NITER - 1 && coltile == 0)
                out[se] = v;        // 64 chunks x 512 = full [B][N]
        }
        __syncthreads();
        buf ^= 1;
    }
}

extern "C" void kernel_launch(void* const* d_in, const int* in_sizes, int n_in,
                              void* d_out, int out_size, void* d_ws, size_t ws_size,
                              hipStream_t stream) {
    const float* preds    = (const float*)d_in[0];   // [B, N]
    const float* P        = (const float*)d_in[1];   // [N, N]
    const int*   seed_idx = (const int*)d_in[2];     // [NSEEDS, 2]
    int nseeds = in_sizes[2] / 2;

    float* out = (float*)d_out;
    float* ws  = (float*)d_ws;

    // zero barrier counters (ws is re-poisoned to 0xAA before every launch)
    hipMemsetAsync(ws, 0, 256, stream);
    diffusion_persistent<<<NBLK, TPB, 0, stream>>>(preds, P, seed_idx, nseeds, out, ws);
}